// Round 8
// baseline (508.743 us; speedup 1.0000x reference)
//
#include <hip/hip_runtime.h>
#include <hip/hip_bf16.h>

// GATv2 x3 layers, MI355X. f32 in/out; edge_index int32.
// R20: FUSED score+aggregate. Block per node d (320 thr = 5 waves = 5 heads);
// lane c owns channel c. Per wave: W column + att hoisted to regs, xd row
// loaded ONCE; per edge-pair (f2): coalesced xs row loads + uniform ea2
// scalar loads -> 16 pk_fma -> packed leaky -> butterfly score reduce ->
// exp -> accumulate w*xs from registers. Eliminates wP buffer, the second
// xs gather pass, k_score, k_wet, k_eacsr, k_selfext (19 -> 12 dispatches).
// CSR pair-boundary edges masked (w=0); self loop scalar path per wave.
// XCD swizzle: contiguous 1250-node slice per XCD (ea2 stream L2-local).
// ws ~= 30.5MB (safe; R17's 48MB faulted).

#define NN 10000    // nodes
#define NE 200000   // edges (even -> NE/2 ea2 pairs)
#define ND 128      // node dim (layer 0 input)
#define ED 16       // edge dim
#define CD 64       // conv dim (per head)
#define NH 5        // heads
#define HC 320      // NH*CD
#define NEG 0.2f

typedef float f2 __attribute__((ext_vector_type(2)));

// ---- CSR build: count ----
__global__ void k_count(const int* __restrict__ dst, int* __restrict__ deg) {
  int e = blockIdx.x * blockDim.x + threadIdx.x;
  if (e >= NE) return;
  atomicAdd(&deg[dst[e]], 1);
}

// ---- CSR build: exclusive scan (single block, 1024 threads x 10 elems) ----
__global__ __launch_bounds__(1024) void k_scan(const int* __restrict__ deg,
                                               int* __restrict__ rowptr) {
  __shared__ int part[1024];
  int t = threadIdx.x;
  int base = t * 10;
  int local[10];
  int s = 0;
  #pragma unroll
  for (int j = 0; j < 10; j++) {
    int i = base + j;
    local[j] = (i < NN) ? deg[i] : 0;
    s += local[j];
  }
  part[t] = s;
  __syncthreads();
  for (int off = 1; off < 1024; off <<= 1) {
    int v = (t >= off) ? part[t - off] : 0;
    __syncthreads();
    part[t] += v;
    __syncthreads();
  }
  int prefix = (t > 0) ? part[t - 1] : 0;
  #pragma unroll
  for (int j = 0; j < 10; j++) {
    int i = base + j;
    if (i < NN) rowptr[i] = prefix;
    prefix += local[j];
  }
  if (t == 1023) rowptr[NN] = prefix;
}

// ---- CSR build: fill (eid for ea2 gather, src for xs gather) ----
__global__ void k_fill(const int* __restrict__ ei, const int* __restrict__ rowptr,
                       int* __restrict__ cursor, int* __restrict__ csr_eid,
                       int* __restrict__ csr_src) {
  int e = blockIdx.x * blockDim.x + threadIdx.x;
  if (e >= NE) return;
  int d = ei[NE + e];
  int slot = atomicAdd(&cursor[d], 1);
  int pos = rowptr[d] + slot;
  csr_eid[pos] = e;
  csr_src[pos] = ei[e];
}

// ---- ea2: pair-interleaved CSR-ordered edge attrs (real edges only) ----
// ea2[(p>>1)*32 + 2*k + (p&1)] = eattr[csr_eid[p]][k]
__global__ void k_ea2(const int* __restrict__ csr_eid, const float* __restrict__ eattr,
                      float* __restrict__ ea2) {
  int idx = blockIdx.x * blockDim.x + threadIdx.x;  // p*16 + k
  if (idx >= NE * ED) return;
  int p = idx >> 4, k = idx & 15;
  float v = eattr[(size_t)csr_eid[p] * ED + k];
  ea2[((size_t)(p >> 1) * 32) + 2 * k + (p & 1)] = v;
}

// ---- loop_attr = mean of incoming edge_attr (reads ea2, CSR-local) ----
__global__ __launch_bounds__(256) void k_loopattr(const float* __restrict__ ea2,
                                                  const int* __restrict__ rowptr,
                                                  float* __restrict__ loop_attr) {
  int wave = threadIdx.x >> 6, lane = threadIdx.x & 63;
  int d = blockIdx.x * 4 + wave;
  if (d >= NN) return;
  int g = lane >> 4, k = lane & 15;
  int b = rowptr[d], n = rowptr[d + 1] - b;
  float s = 0.f;
  for (int i = g; i < n; i += 4) {
    int p = b + i;
    s += ea2[((size_t)(p >> 1) * 32) + 2 * k + (p & 1)];
  }
  s += __shfl_xor(s, 16, 64);
  s += __shfl_xor(s, 32, 64);
  if (g == 0) loop_attr[d * ED + k] = s / fmaxf((float)n, 1.0f);
}

// ---- xl = h @ Wl + bl  (node-major xl[node][hc], contiguous 1280B rows) ----
template <int D>
__global__ __launch_bounds__(320) void k_xl(const float* __restrict__ h,
                                            const float* __restrict__ Wl,
                                            const float* __restrict__ bl,
                                            float* __restrict__ xl) {
  constexpr int NPB = 8;
  int node0 = blockIdx.x * NPB;
  int t = threadIdx.x;  // output column 0..319
  float acc[NPB];
  #pragma unroll
  for (int i = 0; i < NPB; i++) acc[i] = 0.f;
  for (int k = 0; k < D; k += 4) {
    float w0 = Wl[(k + 0) * HC + t];
    float w1 = Wl[(k + 1) * HC + t];
    float w2 = Wl[(k + 2) * HC + t];
    float w3 = Wl[(k + 3) * HC + t];
    #pragma unroll
    for (int i = 0; i < NPB; i++) {
      float4 hv = *(const float4*)(h + (size_t)(node0 + i) * D + k);
      acc[i] += hv.x * w0 + hv.y * w1 + hv.z * w2 + hv.w * w3;
    }
  }
  float bv = bl[t];
  #pragma unroll
  for (int i = 0; i < NPB; i++)
    xl[(size_t)(node0 + i) * HC + t] = acc[i] + bv;
}

// ---- FUSED score+agg: block per node, wave per head, lane per channel ----
__global__ __launch_bounds__(320) void k_fused(
    const int* __restrict__ csr_src, const int* __restrict__ rowptr,
    const float* __restrict__ ea2, const float* __restrict__ loop_attr,
    const float* __restrict__ xl, const float* __restrict__ We,
    const float* __restrict__ att, const float* __restrict__ bias,
    float* __restrict__ out) {
  __shared__ float s_v[NH][CD];
  int bid = blockIdx.x;
  int d = (bid & 7) * (NN / 8) + (bid >> 3);   // contiguous node slice per XCD
  int h = threadIdx.x >> 6, lane = threadIdx.x & 63;
  int b = rowptr[d];
  int pe = rowptr[d + 1];                      // uniform scalars
  // hoist W column (c = lane of head h) and att
  float wv[16];
  #pragma unroll
  for (int k = 0; k < 16; k++) wv[k] = We[k * HC + h * CD + lane];
  float a = att[h * CD + lane];
  const float* xrow = xl + h * CD + lane;      // + node*HC
  float xd = xrow[(size_t)d * HC];             // coalesced, once per node
  const f2 zero = {0.f, 0.f};

  // self loop: z = xd + xd + We . loop_attr[d]
  float dn, acc;
  {
    const float* la = loop_attr + (size_t)d * ED;   // uniform -> s_load
    float z = xd + xd;
    #pragma unroll
    for (int k = 0; k < 16; k++) z += la[k] * wv[k];
    z = fmaxf(z, 0.f) + NEG * fminf(z, 0.f);
    float sc = z * a;
    #pragma unroll
    for (int off = 1; off < 64; off <<= 1) sc += __shfl_xor(sc, off, 64);
    sc = fminf(fmaxf(sc, -60.f), 60.f);
    float w = __expf(sc);
    dn = w;
    acc = w * xd;
  }

  // real edges, processed in globally-aligned pairs (boundary edges masked)
  int tb = b >> 1, te = (pe + 1) >> 1;
  for (int t = tb; t < te; t++) {
    int p0 = 2 * t, p1 = 2 * t + 1;
    int s0 = csr_src[p0], s1 = csr_src[p1];    // uniform -> s_load
    const f2* e2 = (const f2*)(ea2 + (size_t)t * 32);  // uniform rows
    float xs0 = xrow[(size_t)s0 * HC];         // coalesced 256B row
    float xs1 = xrow[(size_t)s1 * HC];
    f2 z = f2{xs0 + xd, xs1 + xd};
    #pragma unroll
    for (int k = 0; k < 16; k++)
      z += e2[k] * f2{wv[k], wv[k]};           // v_pk_fma
    z = __builtin_elementwise_max(z, zero) + NEG * __builtin_elementwise_min(z, zero);
    f2 sc = z * f2{a, a};
    #pragma unroll
    for (int off = 1; off < 64; off <<= 1) {   // butterfly: both edges at once
      sc.x += __shfl_xor(sc.x, off, 64);
      sc.y += __shfl_xor(sc.y, off, 64);
    }
    sc = __builtin_elementwise_min(__builtin_elementwise_max(sc, f2{-60.f, -60.f}),
                                   f2{60.f, 60.f});
    float w0 = (p0 >= b) ? __expf(sc.x) : 0.f; // first-pair mask
    float w1 = (p1 < pe) ? __expf(sc.y) : 0.f; // last-pair mask
    dn += w0 + w1;
    acc += w0 * xs0 + w1 * xs1;
  }

  s_v[h][lane] = acc / dn;
  __syncthreads();
  if (h == 0) {
    float v = s_v[0][lane] + s_v[1][lane] + s_v[2][lane] + s_v[3][lane] + s_v[4][lane];
    v = v * (1.0f / NH) + bias[lane];
    v = v > 0.f ? v : expm1f(v);
    out[(size_t)d * CD + lane] = v;
  }
}

static inline size_t aln(size_t x) { return (x + 255) & ~(size_t)255; }

extern "C" void kernel_launch(void* const* d_in, const int* in_sizes, int n_in,
                              void* d_out, int out_size, void* d_ws, size_t ws_size,
                              hipStream_t stream) {
  const float* x = (const float*)d_in[0];
  const int* ei = (const int*)d_in[1];      // [2, NE]: src row then dst row
  const float* eattr = (const float*)d_in[2];

  char* w = (char*)d_ws;
  int* degi      = (int*)w;                 w += aln(NN * 4);
  int* cursor    = (int*)w;                 w += aln(NN * 4);
  int* rowptr    = (int*)w;                 w += aln((NN + 1) * 4);
  int* csr_eid   = (int*)w;                 w += aln((size_t)NE * 4);
  int* csr_src   = (int*)w;                 w += aln((size_t)NE * 4);
  float* loop_attr = (float*)w;             w += aln((size_t)NN * ED * 4);
  float* ea2     = (float*)w;               w += aln((size_t)NE * ED * 4);
  float* xl      = (float*)w;               w += aln((size_t)NN * HC * 4);
  float* hbuf    = (float*)w;               w += aln((size_t)NN * CD * 4);

  // graph structure + pair-interleaved edge attrs (layer-invariant)
  hipMemsetAsync(degi, 0, NN * 4, stream);
  hipMemsetAsync(cursor, 0, NN * 4, stream);
  k_count<<<(NE + 255) / 256, 256, 0, stream>>>(ei + NE, degi);
  k_scan<<<1, 1024, 0, stream>>>(degi, rowptr);
  k_fill<<<(NE + 255) / 256, 256, 0, stream>>>(ei, rowptr, cursor, csr_eid, csr_src);
  k_ea2<<<(NE * ED + 255) / 256, 256, 0, stream>>>(csr_eid, eattr, ea2);
  k_loopattr<<<(NN + 3) / 4, 256, 0, stream>>>(ea2, rowptr, loop_attr);

  for (int l = 0; l < 3; l++) {
    const float* Wl  = (const float*)d_in[3 + 5 * l];
    const float* bl  = (const float*)d_in[4 + 5 * l];
    const float* We  = (const float*)d_in[5 + 5 * l];
    const float* att = (const float*)d_in[6 + 5 * l];
    const float* b   = (const float*)d_in[7 + 5 * l];

    if (l == 0) k_xl<ND><<<NN / 8, 320, 0, stream>>>(x, Wl, bl, xl);
    else        k_xl<CD><<<NN / 8, 320, 0, stream>>>(hbuf, Wl, bl, xl);

    float* dst_out = (l < 2) ? hbuf : (float*)d_out;
    k_fused<<<NN, 320, 0, stream>>>(csr_src, rowptr, ea2, loop_attr,
                                    xl, We, att, b, dst_out);
  }
}